// Round 2
// baseline (289.176 us; speedup 1.0000x reference)
//
#include <hip/hip_runtime.h>
#include <math.h>

#define B_   128
#define T_   50
#define MI_  32
#define E_   128
#define EW_  16
#define D_   144
#define G_   432        // 3*D
#define N_   (B_*T_)    // 6400

// ---------------------------------------------------------------------------
// K1: basket embedding v2 — parallel gather (unchanged, known good).
// ---------------------------------------------------------------------------
__global__ __launch_bounds__(256) void embed_kernel(
    const int* __restrict__ x,            // [N_][33]
    const float* __restrict__ encode_w,   // [100000][128]  (row 0 == 0)
    const float* __restrict__ wchange_w,  // [2][16]
    float* __restrict__ seq)              // [N_][144]
{
    int n = blockIdx.x;
    int tid = threadIdx.x;
    int i = tid >> 3;        // item 0..31
    int j = tid & 7;         // col chunk [16j, 16j+16)

    __shared__ int xi[33];
    __shared__ __align__(16) float part[32 * 132];  // stride 132 words
    __shared__ float cntf[32];

    if (tid < 33) xi[tid] = x[n * 33 + tid];
    __syncthreads();

    int it = xi[i];
    const float* row = &encode_w[(size_t)it * E_];
    float4 v0 = *(const float4*)&row[16 * j + 0];
    float4 v1 = *(const float4*)&row[16 * j + 4];
    float4 v2 = *(const float4*)&row[16 * j + 8];
    float4 v3 = *(const float4*)&row[16 * j + 12];

    float* p = &part[i * 132 + 16 * j];
    *(float4*)&p[0]  = v0;
    *(float4*)&p[4]  = v1;
    *(float4*)&p[8]  = v2;
    *(float4*)&p[12] = v3;
    if (j == 0) cntf[i] = (it != 0) ? 1.f : 0.f;
    __syncthreads();

    if (tid < E_) {
        int c = tid;
        float s = 0.f, cn = 0.f;
        #pragma unroll
        for (int k = 0; k < 32; ++k) {
            s  += part[k * 132 + c];   // 2-way bank aliasing: free
            cn += cntf[k];             // broadcast: free
        }
        seq[n * D_ + c] = s / fmaxf(cn, 1.f);
    } else if (tid < E_ + EW_) {
        int c = tid - E_;
        seq[n * D_ + E_ + c] = wchange_w[xi[32] * EW_ + c];
    }
}

// ---------------------------------------------------------------------------
// K2: C[M][N] = A[M][144] * Bw[N][144]^T + bias[N].  (unchanged; now only
// used for gi = seq @ w_ih^T + b_ih.)
// ---------------------------------------------------------------------------
#define GK   144
#define GBK  48
#define GPAD 68

__global__ __launch_bounds__(256) void gemm_bias_kernel(
    const float* __restrict__ A,
    const float* __restrict__ Bw,
    const float* __restrict__ bias,
    float* __restrict__ C,
    int M, int N)
{
    __shared__ float As[GBK * GPAD];
    __shared__ float Bs[GBK * GPAD];

    int tid = threadIdx.x;
    int row0 = blockIdx.x * 64;
    int col0 = blockIdx.y * 64;
    int tx = tid & 15;        // col group
    int ty = tid >> 4;        // row group

    float acc[4][4] = {};

    int sr = tid >> 2;
    int skq0 = tid & 3;

    for (int k0 = 0; k0 < GK; k0 += GBK) {
        __syncthreads();
        #pragma unroll
        for (int i = 0; i < 3; ++i) {
            int kq = skq0 + i * 4;          // 0..11  (48 k / 4)
            float4 a = *(const float4*)&A[(size_t)(row0 + sr) * GK + k0 + kq * 4];
            int nrow = col0 + sr;
            float4 b = make_float4(0.f, 0.f, 0.f, 0.f);
            if (nrow < N)
                b = *(const float4*)&Bw[(size_t)nrow * GK + k0 + kq * 4];
            As[(kq * 4 + 0) * GPAD + sr] = a.x;
            As[(kq * 4 + 1) * GPAD + sr] = a.y;
            As[(kq * 4 + 2) * GPAD + sr] = a.z;
            As[(kq * 4 + 3) * GPAD + sr] = a.w;
            Bs[(kq * 4 + 0) * GPAD + sr] = b.x;
            Bs[(kq * 4 + 1) * GPAD + sr] = b.y;
            Bs[(kq * 4 + 2) * GPAD + sr] = b.z;
            Bs[(kq * 4 + 3) * GPAD + sr] = b.w;
        }
        __syncthreads();

        #pragma unroll 4
        for (int k = 0; k < GBK; ++k) {
            float4 a4 = *(const float4*)&As[k * GPAD + ty * 4];
            float4 b4 = *(const float4*)&Bs[k * GPAD + tx * 4];
            float av[4] = {a4.x, a4.y, a4.z, a4.w};
            float bv[4] = {b4.x, b4.y, b4.z, b4.w};
            #pragma unroll
            for (int i = 0; i < 4; ++i)
                #pragma unroll
                for (int j = 0; j < 4; ++j)
                    acc[i][j] = fmaf(av[i], bv[j], acc[i][j]);
        }
    }

    int c = col0 + tx * 4;
    if (c < N) {
        float4 bb = *(const float4*)&bias[c];
        #pragma unroll
        for (int i = 0; i < 4; ++i) {
            int r = row0 + ty * 4 + i;
            float4 o;
            o.x = acc[i][0] + bb.x;
            o.y = acc[i][1] + bb.y;
            o.z = acc[i][2] + bb.z;
            o.w = acc[i][3] + bb.w;
            *(float4*)&C[(size_t)r * N + c] = o;
        }
    }
}

// ---------------------------------------------------------------------------
// K3: GRU v5 = exact v3 structure (measured 54.3us; elementwise in tid<144
// so waves 3..8 skip it via execz — v4's all-wave masked elementwise cost
// +3.4us) + FUSED fc output head (was K4):
//   dyn[n] = fc_w @ h_t + fc_b
// The hv[20] chunk each lane loads for step t's gh dot IS h_{t-1}, exactly
// what fc needs for output row t-1 -> fc rides the existing LDS read for
// free.  Groups g<64 hold fc rows {2g,2g+1} weights-stationary (40 VGPR),
// +40 FMA + 2 butterflies per step (~110cyc/wave, hidden in the step's
// stall budget).  Wave 8 (g>=64) skips fc via a wave-uniform branch.
// fc lags one step (row t-1 emitted at iter t); epilogue emits row T-1.
// Deletes: K4 launch, hseq global write (3.7MB), hseq re-read (3.7MB).
// ---------------------------------------------------------------------------
template<int CTRL>
__device__ __forceinline__ float dpp_xor_add(float x) {
    int y = __builtin_amdgcn_mov_dpp(__float_as_int(x), CTRL, 0xF, 0xF, true);
    return x + __int_as_float(y);
}

__global__ __launch_bounds__(576) void gru_kernel(
    const float* __restrict__ gi,     // [N_][432]
    const float* __restrict__ w_hh,   // [432][144]
    const float* __restrict__ b_hh,   // [432]
    const float* __restrict__ h0,     // [128][144]
    const float* __restrict__ fc_w,   // [128][144]
    const float* __restrict__ fc_b,   // [128]
    float* __restrict__ dyn,          // [N_][128]  (dynamic_user, final out)
    float* __restrict__ hlast)        // [128][144]
{
    int b = blockIdx.x;
    int tid = threadIdx.x;
    int g = tid >> 3;       // 0..71  -> gh rows 6g..6g+5
    int s = tid & 7;        // k-chunk [20s, 20s+20)
    int k0 = s * 20;

    __shared__ __align__(16) float h[160];   // k-padded; [144..159] stay 0
    __shared__ float gh[G_];

    // one-time: w_hh rows into VGPRs (zero-padded past k=143)
    float w[6][20];
    #pragma unroll
    for (int r = 0; r < 6; ++r) {
        const float* wrow = &w_hh[(size_t)(6 * g + r) * D_];
        #pragma unroll
        for (int q = 0; q < 5; ++q) {
            int k = k0 + 4 * q;
            float4 t = make_float4(0.f, 0.f, 0.f, 0.f);
            if (k < D_) t = *(const float4*)&wrow[k];   // k<=140, safe
            w[r][4 * q + 0] = t.x;
            w[r][4 * q + 1] = t.y;
            w[r][4 * q + 2] = t.z;
            w[r][4 * q + 3] = t.w;
        }
    }
    float bias = (s < 6) ? b_hh[6 * g + s] : 0.f;

    // one-time: fc rows {2g, 2g+1} for groups g<64 (zeros otherwise)
    float wf[2][20];
    #pragma unroll
    for (int r = 0; r < 2; ++r) {
        #pragma unroll
        for (int q = 0; q < 5; ++q) {
            int k = k0 + 4 * q;
            float4 t = make_float4(0.f, 0.f, 0.f, 0.f);
            if (g < 64 && k < D_)
                t = *(const float4*)&fc_w[(size_t)(2 * g + r) * D_ + k];
            wf[r][4 * q + 0] = t.x;
            wf[r][4 * q + 1] = t.y;
            wf[r][4 * q + 2] = t.z;
            wf[r][4 * q + 3] = t.w;
        }
    }
    float fbias = (g < 64 && s < 2) ? fc_b[2 * g + s] : 0.f;

    if (tid < 160) h[tid] = (tid < D_) ? h0[b * D_ + tid] : 0.f;
    __syncthreads();

    for (int t = 0; t < T_; ++t) {
        int n = b * T_ + t;
        // prefetch gi (L2-resident; overlaps the LDS reads + dot phase)
        float gir = 0.f, giz = 0.f, gin = 0.f;
        if (tid < D_) {
            gir = gi[(size_t)n * G_ + tid];
            giz = gi[(size_t)n * G_ + D_ + tid];
            gin = gi[(size_t)n * G_ + 2 * D_ + tid];
        }

        // h chunk (= h_{t-1}): 5 conflict-free ds_read_b128
        float hv[20];
        #pragma unroll
        for (int q = 0; q < 5; ++q) {
            float4 t4 = *(const float4*)&h[k0 + 4 * q];
            hv[4 * q + 0] = t4.x;
            hv[4 * q + 1] = t4.y;
            hv[4 * q + 2] = t4.z;
            hv[4 * q + 3] = t4.w;
        }

        // 6 rows x 20 k partial dots (120 fmac, 6 independent chains)
        float a0 = 0.f, a1 = 0.f, a2 = 0.f, a3 = 0.f, a4 = 0.f, a5 = 0.f;
        #pragma unroll
        for (int kk = 0; kk < 20; ++kk) {
            float hk = hv[kk];
            a0 = fmaf(w[0][kk], hk, a0);
            a1 = fmaf(w[1][kk], hk, a1);
            a2 = fmaf(w[2][kk], hk, a2);
            a3 = fmaf(w[3][kk], hk, a3);
            a4 = fmaf(w[4][kk], hk, a4);
            a5 = fmaf(w[5][kk], hk, a5);
        }

        // reduce across the 8 k-chunk lanes: VALU DPP butterfly (no LDS)
        a0 = dpp_xor_add<0xB1>(a0); a0 = dpp_xor_add<0x4E>(a0); a0 = dpp_xor_add<0x141>(a0);
        a1 = dpp_xor_add<0xB1>(a1); a1 = dpp_xor_add<0x4E>(a1); a1 = dpp_xor_add<0x141>(a1);
        a2 = dpp_xor_add<0xB1>(a2); a2 = dpp_xor_add<0x4E>(a2); a2 = dpp_xor_add<0x141>(a2);
        a3 = dpp_xor_add<0xB1>(a3); a3 = dpp_xor_add<0x4E>(a3); a3 = dpp_xor_add<0x141>(a3);
        a4 = dpp_xor_add<0xB1>(a4); a4 = dpp_xor_add<0x4E>(a4); a4 = dpp_xor_add<0x141>(a4);
        a5 = dpp_xor_add<0xB1>(a5); a5 = dpp_xor_add<0x4E>(a5); a5 = dpp_xor_add<0x141>(a5);

        // lane s writes row 6g+s (s<6); all 8 lanes hold all 6 sums
        float myacc = a0;
        if (s == 1) myacc = a1;
        if (s == 2) myacc = a2;
        if (s == 3) myacc = a3;
        if (s == 4) myacc = a4;
        if (s == 5) myacc = a5;
        if (s < 6) gh[6 * g + s] = myacc + bias;

        // fused fc head on hv = h_{t-1}: output row t-1 (t>=1).
        // wave-uniform branch: wave 8 (g>=64) skips entirely.
        if (g < 64) {
            float f0 = 0.f, f1 = 0.f;
            #pragma unroll
            for (int kk = 0; kk < 20; ++kk) {
                float hk = hv[kk];
                f0 = fmaf(wf[0][kk], hk, f0);
                f1 = fmaf(wf[1][kk], hk, f1);
            }
            f0 = dpp_xor_add<0xB1>(f0); f0 = dpp_xor_add<0x4E>(f0); f0 = dpp_xor_add<0x141>(f0);
            f1 = dpp_xor_add<0xB1>(f1); f1 = dpp_xor_add<0x4E>(f1); f1 = dpp_xor_add<0x141>(f1);
            if (t > 0 && s < 2)
                dyn[(size_t)(n - 1) * E_ + 2 * g + s] = ((s == 0) ? f0 : f1) + fbias;
        }
        __syncthreads();

        if (tid < D_) {
            float r = 1.f / (1.f + __expf(-(gir + gh[tid])));
            float z = 1.f / (1.f + __expf(-(giz + gh[D_ + tid])));
            float narg = gin + r * gh[2 * D_ + tid];
            narg = fminf(fmaxf(narg, -15.f), 15.f);
            float e2 = __expf(-2.f * narg);
            float nn = (1.f - e2) / (1.f + e2);
            float hn = (1.f - z) * nn + z * h[tid];
            h[tid] = hn;
        }
        __syncthreads();
    }

    // epilogue: fc for the last step's h (h_{T-1}), and hlast
    if (g < 64) {
        float hv[20];
        #pragma unroll
        for (int q = 0; q < 5; ++q) {
            float4 t4 = *(const float4*)&h[k0 + 4 * q];
            hv[4 * q + 0] = t4.x;
            hv[4 * q + 1] = t4.y;
            hv[4 * q + 2] = t4.z;
            hv[4 * q + 3] = t4.w;
        }
        float f0 = 0.f, f1 = 0.f;
        #pragma unroll
        for (int kk = 0; kk < 20; ++kk) {
            float hk = hv[kk];
            f0 = fmaf(wf[0][kk], hk, f0);
            f1 = fmaf(wf[1][kk], hk, f1);
        }
        f0 = dpp_xor_add<0xB1>(f0); f0 = dpp_xor_add<0x4E>(f0); f0 = dpp_xor_add<0x141>(f0);
        f1 = dpp_xor_add<0xB1>(f1); f1 = dpp_xor_add<0x4E>(f1); f1 = dpp_xor_add<0x141>(f1);
        if (s < 2)
            dyn[(size_t)(b * T_ + T_ - 1) * E_ + 2 * g + s] = ((s == 0) ? f0 : f1) + fbias;
    }
    if (tid < D_) hlast[b * D_ + tid] = h[tid];
}

// ---------------------------------------------------------------------------
extern "C" void kernel_launch(void* const* d_in, const int* in_sizes, int n_in,
                              void* d_out, int out_size, void* d_ws, size_t ws_size,
                              hipStream_t stream)
{
    const int*   x         = (const int*)d_in[0];
    // d_in[1] = lengths (unused by the reference computation)
    const float* hidden    = (const float*)d_in[2];
    const float* encode_w  = (const float*)d_in[3];
    const float* wchange_w = (const float*)d_in[4];
    const float* w_ih      = (const float*)d_in[5];
    const float* w_hh      = (const float*)d_in[6];
    const float* b_ih      = (const float*)d_in[7];
    const float* b_hh      = (const float*)d_in[8];
    const float* fc_w      = (const float*)d_in[9];
    const float* fc_b      = (const float*)d_in[10];

    float* out = (float*)d_out;              // [N_][128] then [128][144]
    float* ws  = (float*)d_ws;
    float* seq  = ws;                        //   921600 floats
    float* gi   = ws + 921600;               //  2764800 floats

    // K1: embedding (parallel gather v2)
    embed_kernel<<<N_, 256, 0, stream>>>(x, encode_w, wchange_w, seq);

    // K2: gi = seq @ w_ih^T + b_ih   (M=6400, N=432)
    gemm_bias_kernel<<<dim3(N_ / 64, (G_ + 63) / 64), 256, 0, stream>>>(
        seq, w_ih, b_ih, gi, N_, G_);

    // K3: GRU over T=50 with fused fc head (K4 deleted)
    gru_kernel<<<B_, 576, 0, stream>>>(gi, w_hh, b_hh, hidden, fc_w, fc_b,
                                       out, out + (size_t)N_ * E_);
}

// Round 3
// 187.025 us; speedup vs baseline: 1.5462x; 1.5462x over previous
//
#include <hip/hip_runtime.h>
#include <math.h>

#define B_   128
#define T_   50
#define MI_  32
#define E_   128
#define EW_  16
#define D_   144
#define G_   432        // 3*D
#define N_   (B_*T_)    // 6400

// ---------------------------------------------------------------------------
// K1: basket embedding v2 — parallel gather (unchanged, known good).
// ---------------------------------------------------------------------------
__global__ __launch_bounds__(256) void embed_kernel(
    const int* __restrict__ x,            // [N_][33]
    const float* __restrict__ encode_w,   // [100000][128]  (row 0 == 0)
    const float* __restrict__ wchange_w,  // [2][16]
    float* __restrict__ seq)              // [N_][144]
{
    int n = blockIdx.x;
    int tid = threadIdx.x;
    int i = tid >> 3;        // item 0..31
    int j = tid & 7;         // col chunk [16j, 16j+16)

    __shared__ int xi[33];
    __shared__ __align__(16) float part[32 * 132];  // stride 132 words
    __shared__ float cntf[32];

    if (tid < 33) xi[tid] = x[n * 33 + tid];
    __syncthreads();

    int it = xi[i];
    const float* row = &encode_w[(size_t)it * E_];
    float4 v0 = *(const float4*)&row[16 * j + 0];
    float4 v1 = *(const float4*)&row[16 * j + 4];
    float4 v2 = *(const float4*)&row[16 * j + 8];
    float4 v3 = *(const float4*)&row[16 * j + 12];

    float* p = &part[i * 132 + 16 * j];
    *(float4*)&p[0]  = v0;
    *(float4*)&p[4]  = v1;
    *(float4*)&p[8]  = v2;
    *(float4*)&p[12] = v3;
    if (j == 0) cntf[i] = (it != 0) ? 1.f : 0.f;
    __syncthreads();

    if (tid < E_) {
        int c = tid;
        float s = 0.f, cn = 0.f;
        #pragma unroll
        for (int k = 0; k < 32; ++k) {
            s  += part[k * 132 + c];   // 2-way bank aliasing: free
            cn += cntf[k];             // broadcast: free
        }
        seq[n * D_ + c] = s / fmaxf(cn, 1.f);
    } else if (tid < E_ + EW_) {
        int c = tid - E_;
        seq[n * D_ + E_ + c] = wchange_w[xi[32] * EW_ + c];
    }
}

// ---------------------------------------------------------------------------
// K2/K4: C[M][N] = A[M][144] * Bw[N][144]^T + bias[N].  K fixed = 144.
// 64x64 tile, k-major LDS (pad 68 words -> conflict-free b128 reads), BK=48.
// ---------------------------------------------------------------------------
#define GK   144
#define GBK  48
#define GPAD 68

__global__ __launch_bounds__(256) void gemm_bias_kernel(
    const float* __restrict__ A,
    const float* __restrict__ Bw,
    const float* __restrict__ bias,
    float* __restrict__ C,
    int M, int N)
{
    __shared__ float As[GBK * GPAD];
    __shared__ float Bs[GBK * GPAD];

    int tid = threadIdx.x;
    int row0 = blockIdx.x * 64;
    int col0 = blockIdx.y * 64;
    int tx = tid & 15;        // col group
    int ty = tid >> 4;        // row group

    float acc[4][4] = {};

    int sr = tid >> 2;
    int skq0 = tid & 3;

    for (int k0 = 0; k0 < GK; k0 += GBK) {
        __syncthreads();
        #pragma unroll
        for (int i = 0; i < 3; ++i) {
            int kq = skq0 + i * 4;          // 0..11  (48 k / 4)
            float4 a = *(const float4*)&A[(size_t)(row0 + sr) * GK + k0 + kq * 4];
            int nrow = col0 + sr;
            float4 b = make_float4(0.f, 0.f, 0.f, 0.f);
            if (nrow < N)
                b = *(const float4*)&Bw[(size_t)nrow * GK + k0 + kq * 4];
            As[(kq * 4 + 0) * GPAD + sr] = a.x;
            As[(kq * 4 + 1) * GPAD + sr] = a.y;
            As[(kq * 4 + 2) * GPAD + sr] = a.z;
            As[(kq * 4 + 3) * GPAD + sr] = a.w;
            Bs[(kq * 4 + 0) * GPAD + sr] = b.x;
            Bs[(kq * 4 + 1) * GPAD + sr] = b.y;
            Bs[(kq * 4 + 2) * GPAD + sr] = b.z;
            Bs[(kq * 4 + 3) * GPAD + sr] = b.w;
        }
        __syncthreads();

        #pragma unroll 4
        for (int k = 0; k < GBK; ++k) {
            float4 a4 = *(const float4*)&As[k * GPAD + ty * 4];
            float4 b4 = *(const float4*)&Bs[k * GPAD + tx * 4];
            float av[4] = {a4.x, a4.y, a4.z, a4.w};
            float bv[4] = {b4.x, b4.y, b4.z, b4.w};
            #pragma unroll
            for (int i = 0; i < 4; ++i)
                #pragma unroll
                for (int j = 0; j < 4; ++j)
                    acc[i][j] = fmaf(av[i], bv[j], acc[i][j]);
        }
    }

    int c = col0 + tx * 4;
    if (c < N) {
        float4 bb = *(const float4*)&bias[c];
        #pragma unroll
        for (int i = 0; i < 4; ++i) {
            int r = row0 + ty * 4 + i;
            float4 o;
            o.x = acc[i][0] + bb.x;
            o.y = acc[i][1] + bb.y;
            o.z = acc[i][2] + bb.z;
            o.w = acc[i][3] + bb.w;
            *(float4*)&C[(size_t)r * N + c] = o;
        }
    }
}

// ---------------------------------------------------------------------------
// K3: GRU v6 = exact v3 structure (measured 54.3us) + gi prefetched ONE FULL
// STEP ahead (+3 VGPR only).
// Lessons enforced here:
//  - v4: elementwise must stay DENSE in tid<144 (waves 3..8 skip via execz);
//    masking it s<2 across all 9 waves costs +3.5-4us of issue.
//  - v5: NO extra resident weight arrays — w[6][20]+hv[20] already sits at
//    the ~170-reg/lane cap for 9 waves; +42 regs spilled to scratch and
//    tripled the kernel (VALUBusy 32->12%, HBM counters inflated by spill
//    leakage).  fc stays in K4.
//  - prefetch: loads issued at top of A(t) drain at bar1(t) regardless
//    (compiler emits vmcnt(0) before s_barrier).  v3 consumed them in B(t)
//    -> any gi latency beyond the ~750cyc dot phase stalled bar1 every
//    step.  v6 issues t+1's gi there instead; consumed in B(t+1), a full
//    step later -> zero exposed latency, identical issue count.
// ---------------------------------------------------------------------------
template<int CTRL>
__device__ __forceinline__ float dpp_xor_add(float x) {
    int y = __builtin_amdgcn_mov_dpp(__float_as_int(x), CTRL, 0xF, 0xF, true);
    return x + __int_as_float(y);
}

__global__ __launch_bounds__(576) void gru_kernel(
    const float* __restrict__ gi,     // [N_][432]
    const float* __restrict__ w_hh,   // [432][144]
    const float* __restrict__ b_hh,   // [432]
    const float* __restrict__ h0,     // [128][144]
    float* __restrict__ hseq,         // [N_][144]
    float* __restrict__ hlast)        // [128][144]
{
    int b = blockIdx.x;
    int tid = threadIdx.x;
    int g = tid >> 3;       // 0..71  -> rows 6g..6g+5
    int s = tid & 7;        // k-chunk [20s, 20s+20)
    int k0 = s * 20;

    __shared__ __align__(16) float h[160];   // k-padded; [144..159] stay 0
    __shared__ float gh[G_];

    // one-time: weights into VGPRs (zero-padded past k=143)
    float w[6][20];
    #pragma unroll
    for (int r = 0; r < 6; ++r) {
        const float* wrow = &w_hh[(size_t)(6 * g + r) * D_];
        #pragma unroll
        for (int q = 0; q < 5; ++q) {
            int k = k0 + 4 * q;
            float4 t = make_float4(0.f, 0.f, 0.f, 0.f);
            if (k < D_) t = *(const float4*)&wrow[k];   // k<=140, safe
            w[r][4 * q + 0] = t.x;
            w[r][4 * q + 1] = t.y;
            w[r][4 * q + 2] = t.z;
            w[r][4 * q + 3] = t.w;
        }
    }
    float bias = (s < 6) ? b_hh[6 * g + s] : 0.f;

    if (tid < 160) h[tid] = (tid < D_) ? h0[b * D_ + tid] : 0.f;
    __syncthreads();

    // gi pipeline: registers hold step t's values at top of iteration t;
    // preload t=0 here.
    float gir = 0.f, giz = 0.f, gin = 0.f;
    if (tid < D_) {
        const float* gp = &gi[(size_t)(b * T_) * G_];
        gir = gp[tid];
        giz = gp[D_ + tid];
        gin = gp[2 * D_ + tid];
    }

    for (int t = 0; t < T_; ++t) {
        int n = b * T_ + t;

        // rotate pipeline: consume regs for step t, issue loads for t+1.
        // These loads drain at bar1(t) but are used in B(t+1) -> fully hidden.
        float girU = gir, gizU = giz, ginU = gin;
        if (tid < D_ && t + 1 < T_) {
            const float* gp = &gi[(size_t)(n + 1) * G_];
            gir = gp[tid];
            giz = gp[D_ + tid];
            gin = gp[2 * D_ + tid];
        }

        // h chunk: 5 conflict-free ds_read_b128
        float hv[20];
        #pragma unroll
        for (int q = 0; q < 5; ++q) {
            float4 t4 = *(const float4*)&h[k0 + 4 * q];
            hv[4 * q + 0] = t4.x;
            hv[4 * q + 1] = t4.y;
            hv[4 * q + 2] = t4.z;
            hv[4 * q + 3] = t4.w;
        }

        // 6 rows x 20 k partial dots (120 fmac, 6 independent chains)
        float a0 = 0.f, a1 = 0.f, a2 = 0.f, a3 = 0.f, a4 = 0.f, a5 = 0.f;
        #pragma unroll
        for (int kk = 0; kk < 20; ++kk) {
            float hk = hv[kk];
            a0 = fmaf(w[0][kk], hk, a0);
            a1 = fmaf(w[1][kk], hk, a1);
            a2 = fmaf(w[2][kk], hk, a2);
            a3 = fmaf(w[3][kk], hk, a3);
            a4 = fmaf(w[4][kk], hk, a4);
            a5 = fmaf(w[5][kk], hk, a5);
        }

        // reduce across the 8 k-chunk lanes: VALU DPP butterfly (no LDS)
        a0 = dpp_xor_add<0xB1>(a0); a0 = dpp_xor_add<0x4E>(a0); a0 = dpp_xor_add<0x141>(a0);
        a1 = dpp_xor_add<0xB1>(a1); a1 = dpp_xor_add<0x4E>(a1); a1 = dpp_xor_add<0x141>(a1);
        a2 = dpp_xor_add<0xB1>(a2); a2 = dpp_xor_add<0x4E>(a2); a2 = dpp_xor_add<0x141>(a2);
        a3 = dpp_xor_add<0xB1>(a3); a3 = dpp_xor_add<0x4E>(a3); a3 = dpp_xor_add<0x141>(a3);
        a4 = dpp_xor_add<0xB1>(a4); a4 = dpp_xor_add<0x4E>(a4); a4 = dpp_xor_add<0x141>(a4);
        a5 = dpp_xor_add<0xB1>(a5); a5 = dpp_xor_add<0x4E>(a5); a5 = dpp_xor_add<0x141>(a5);

        // lane s writes row 6g+s (s<6); all 8 lanes hold all 6 sums
        float myacc = a0;
        if (s == 1) myacc = a1;
        if (s == 2) myacc = a2;
        if (s == 3) myacc = a3;
        if (s == 4) myacc = a4;
        if (s == 5) myacc = a5;
        if (s < 6) gh[6 * g + s] = myacc + bias;
        __syncthreads();

        if (tid < D_) {
            float r = 1.f / (1.f + __expf(-(girU + gh[tid])));
            float z = 1.f / (1.f + __expf(-(gizU + gh[D_ + tid])));
            float narg = ginU + r * gh[2 * D_ + tid];
            narg = fminf(fmaxf(narg, -15.f), 15.f);
            float e2 = __expf(-2.f * narg);
            float nn = (1.f - e2) / (1.f + e2);
            float hn = (1.f - z) * nn + z * h[tid];
            hseq[(size_t)n * D_ + tid] = hn;
            h[tid] = hn;
        }
        __syncthreads();
    }

    if (tid < D_) hlast[b * D_ + tid] = h[tid];
}

// ---------------------------------------------------------------------------
extern "C" void kernel_launch(void* const* d_in, const int* in_sizes, int n_in,
                              void* d_out, int out_size, void* d_ws, size_t ws_size,
                              hipStream_t stream)
{
    const int*   x         = (const int*)d_in[0];
    // d_in[1] = lengths (unused by the reference computation)
    const float* hidden    = (const float*)d_in[2];
    const float* encode_w  = (const float*)d_in[3];
    const float* wchange_w = (const float*)d_in[4];
    const float* w_ih      = (const float*)d_in[5];
    const float* w_hh      = (const float*)d_in[6];
    const float* b_ih      = (const float*)d_in[7];
    const float* b_hh      = (const float*)d_in[8];
    const float* fc_w      = (const float*)d_in[9];
    const float* fc_b      = (const float*)d_in[10];

    float* out = (float*)d_out;              // [N_][128] then [128][144]
    float* ws  = (float*)d_ws;
    float* seq  = ws;                        //   921600 floats
    float* gi   = ws + 921600;               //  2764800 floats
    float* hseq = ws + 921600 + 2764800;     //   921600 floats  (18.4 MB total)

    // K1: embedding (parallel gather v2)
    embed_kernel<<<N_, 256, 0, stream>>>(x, encode_w, wchange_w, seq);

    // K2: gi = seq @ w_ih^T + b_ih   (M=6400, N=432)
    gemm_bias_kernel<<<dim3(N_ / 64, (G_ + 63) / 64), 256, 0, stream>>>(
        seq, w_ih, b_ih, gi, N_, G_);

    // K3: GRU over T=50 (v6 = v3 + 1-step-ahead gi pipeline)
    gru_kernel<<<B_, 576, 0, stream>>>(gi, w_hh, b_hh, hidden, hseq,
                                       out + (size_t)N_ * E_);

    // K4: dynamic_user = hseq @ fc_w^T + fc_b   (M=6400, N=128)
    gemm_bias_kernel<<<dim3(N_ / 64, E_ / 64), 256, 0, stream>>>(
        hseq, fc_w, fc_b, out, N_, E_);
}